// Round 7
// baseline (405.877 us; speedup 1.0000x reference)
//
#include <hip/hip_runtime.h>
#include <hip/hip_bf16.h>
#include <stdint.h>

typedef __hip_bfloat16 bf16;
typedef __attribute__((ext_vector_type(8))) short short8;
typedef __attribute__((ext_vector_type(4))) float f32x4;

#define NEG 0.2f
#define LN_EPS 1e-5f

__device__ __forceinline__ float bits2f(unsigned b) {  // low 16 bits = bf16
    return __uint_as_float(b << 16);
}
__device__ __forceinline__ float hi2f(unsigned b) {    // high 16 bits = bf16
    return __uint_as_float(b & 0xffff0000u);
}
__device__ __forceinline__ unsigned short f2b_bits(float f) {  // RNE f32->bf16 bits
    unsigned u = __float_as_uint(f);
    unsigned r = u + 0x7fffu + ((u >> 16) & 1u);
    return (unsigned short)(r >> 16);
}
__device__ __forceinline__ float lrelu(float v) {
    return fmaxf(v, 0.f) + NEG * fminf(v, 0.f);
}
__device__ __forceinline__ void unpack8(uint4 u, float* v) {
    v[0] = bits2f(u.x); v[1] = hi2f(u.x);
    v[2] = bits2f(u.y); v[3] = hi2f(u.y);
    v[4] = bits2f(u.z); v[5] = hi2f(u.z);
    v[6] = bits2f(u.w); v[7] = hi2f(u.w);
}

union S8 { uint4 u; short8 s; unsigned short us[8]; };
__device__ __forceinline__ short8 ld8b(const char* p) {
    S8 c; c.u = *(const uint4*)p; return c.s;
}
__device__ __forceinline__ short8 ld8f(const float* p) {
    float4 a = ((const float4*)p)[0], b = ((const float4*)p)[1];
    S8 c;
    c.us[0] = f2b_bits(a.x); c.us[1] = f2b_bits(a.y);
    c.us[2] = f2b_bits(a.z); c.us[3] = f2b_bits(a.w);
    c.us[4] = f2b_bits(b.x); c.us[5] = f2b_bits(b.y);
    c.us[6] = f2b_bits(b.z); c.us[7] = f2b_bits(b.w);
    return c.s;
}

// ---- K0: detect float dtype (flags[0]=1 -> bf16) and index width (flags[1]=1 -> int64)
__global__ void detect_kernel(const unsigned* __restrict__ xw, const int* __restrict__ ei,
                              int* __restrict__ flags, int E) {
    int lane = threadIdx.x;  // 64 threads
    int sane = 0;
    for (int k = 0; k < 4; ++k) {
        unsigned short lo = (unsigned short)(xw[k * 64 + lane] & 0xFFFFu);
        int ex = (lo >> 7) & 0xFF;
        if (lo == 0 || (ex > 100 && ex < 155)) sane++;
    }
#pragma unroll
    for (int off = 32; off > 0; off >>= 1) sane += __shfl_xor(sane, off);
    int nchk = E < 64 ? E : 64;
    int bad = (lane < nchk) ? (ei[2 * lane + 1] != 0) : 0;
    unsigned long long bb = __ballot(bad);
    if (lane == 0) {
        flags[0] = (sane > 200) ? 1 : 0;
        flags[1] = (bb == 0ULL) ? 1 : 0;
    }
}

// ---- K1: consolidated prep: weight transposes (raw -> bf16 W^T), small cvt, deg init
struct PrepArgs {
    const void* Wl; const void* Wr; const void* W1; const void* W2;
    const void* ssrc[8];   // b_l, b_r, att, gat_bias, ln_g, ln_b, b1, b2
    unsigned short* Wlt; unsigned short* Wrt; unsigned short* W1t; unsigned short* W2t;
    float* smalls;         // 2304 floats
    int* deg;
    int N;
};
__global__ __launch_bounds__(256) void prep_kernel(PrepArgs a, const int* __restrict__ flags) {
    int isb = flags[0];
    int i = blockIdx.x * 256 + threadIdx.x;
    int seg = blockIdx.y;
    if (seg == 0) {         // Wlt[c*128+k] <- W_l[k*512+c], 512x128
        if (i < 512 * 128) {
            int c = i >> 7, k = i & 127;
            a.Wlt[i] = isb ? ((const unsigned short*)a.Wl)[k * 512 + c]
                           : f2b_bits(((const float*)a.Wl)[k * 512 + c]);
        }
    } else if (seg == 1) {  // Wrt
        if (i < 512 * 128) {
            int c = i >> 7, k = i & 127;
            a.Wrt[i] = isb ? ((const unsigned short*)a.Wr)[k * 512 + c]
                           : f2b_bits(((const float*)a.Wr)[k * 512 + c]);
        }
    } else if (seg == 2) {  // W1t[c*128+k] <- W1[k*256+c], 256x128
        if (i < 256 * 128) {
            int c = i >> 7, k = i & 127;
            a.W1t[i] = isb ? ((const unsigned short*)a.W1)[k * 256 + c]
                           : f2b_bits(((const float*)a.W1)[k * 256 + c]);
        }
    } else if (seg == 3) {  // W2t[c*256+k] <- W2[k*128+c], 128x256
        if (i < 128 * 256) {
            int c = i >> 8, k = i & 255;
            a.W2t[i] = isb ? ((const unsigned short*)a.W2)[k * 128 + c]
                           : f2b_bits(((const float*)a.W2)[k * 128 + c]);
        }
    } else if (seg == 4) {  // deg init (self-loop)
        if (i < a.N) a.deg[i] = 1;
    } else {                // smalls cvt: sizes 512,512,512,128,128,128,256,128
        const int sn[8] = {512, 512, 512, 128, 128, 128, 256, 128};
        int off = 0;
        for (int t = 0; t < 8; ++t) {
            if (i < off + sn[t]) {
                int j = i - off;
                a.smalls[i] = isb ? bits2f(((const unsigned short*)a.ssrc[t])[j])
                                  : ((const float*)a.ssrc[t])[j];
                return;
            }
            off += sn[t];
        }
    }
}

// ================= MFMA GEMM =================
// A (16x32): lane holds A[m=lane&15][k=quad*8+j]; B (32x16): B[k=quad*8+j][n=lane&15]
// C/D: reg j -> row=quad*4+j, col=lane&15.  (m89/m91-verified)
// Wave tile 64x64 (4 row-frags x 4 col-frags), block = 2x2 waves = 128x128.
// Per K-step: 8 global loads feed 16 MFMAs (B reused over 4 row-frags).

// ---- K2: merged proj: grid.y 0-3 -> xl (Wlt, b_l), 4-7 -> xr (Wrt, b_r); 128-col blocks
__global__ __launch_bounds__(256) void proj_mfma_kernel(
    const void* __restrict__ xv, const unsigned short* __restrict__ Wlt,
    const unsigned short* __restrict__ Wrt, const float* __restrict__ smalls,
    unsigned short* __restrict__ xl, unsigned short* __restrict__ xr,
    int N, const int* __restrict__ flags) {
    int isb = flags[0];
    int half = blockIdx.y >> 2;
    const unsigned short* Wt = half ? Wrt : Wlt;
    const float* bias = smalls + (half ? 512 : 0);
    unsigned short* out = half ? xr : xl;
    int wid = threadIdx.x >> 6, lane = threadIdx.x & 63;
    int quad = lane >> 4, l16 = lane & 15;
    int m0 = blockIdx.x * 128 + (wid >> 1) * 64;
    int n0 = (blockIdx.y & 3) * 128 + (wid & 1) * 64;

    int ra[4];
#pragma unroll
    for (int rf = 0; rf < 4; ++rf) {
        int r = m0 + rf * 16 + l16;
        ra[rf] = (r < N) ? r : N - 1;
    }

    f32x4 acc[4][4];
#pragma unroll
    for (int rf = 0; rf < 4; ++rf)
#pragma unroll
        for (int c = 0; c < 4; ++c) acc[rf][c] = (f32x4){0.f, 0.f, 0.f, 0.f};

#pragma unroll
    for (int kk = 0; kk < 128; kk += 32) {
        short8 a[4], b[4];
#pragma unroll
        for (int rf = 0; rf < 4; ++rf) {
            if (isb) a[rf] = ld8b((const char*)xv + ((size_t)ra[rf] * 128 + kk + quad * 8) * 2);
            else     a[rf] = ld8f((const float*)xv + (size_t)ra[rf] * 128 + kk + quad * 8);
        }
#pragma unroll
        for (int c = 0; c < 4; ++c)
            b[c] = ld8b((const char*)(Wt + (size_t)(n0 + c * 16 + l16) * 128 + kk + quad * 8));
#pragma unroll
        for (int rf = 0; rf < 4; ++rf)
#pragma unroll
            for (int c = 0; c < 4; ++c)
                acc[rf][c] = __builtin_amdgcn_mfma_f32_16x16x32_bf16(a[rf], b[c], acc[rf][c], 0, 0, 0);
    }
#pragma unroll
    for (int c = 0; c < 4; ++c) {
        int col = n0 + c * 16 + l16;
        float bv = bias[col];
#pragma unroll
        for (int rf = 0; rf < 4; ++rf) {
#pragma unroll
            for (int j = 0; j < 4; ++j) {
                int row = m0 + rf * 16 + quad * 4 + j;
                if (row < N) out[(size_t)row * 512 + col] = f2b_bits(acc[rf][c][j] + bv);
            }
        }
    }
}

// ---- CSR build ----
__global__ __launch_bounds__(256) void hist_kernel(const int* __restrict__ ei,
                                                   int* __restrict__ deg,
                                                   const int* __restrict__ flags,
                                                   int E, int N) {
    int e = blockIdx.x * 256 + threadIdx.x;
    if (e >= E) return;
    int d = flags[1] ? ei[2 * (size_t)E + 2 * (size_t)e] : ei[(size_t)E + e];
    if ((unsigned)d >= (unsigned)N) d = 0;
    atomicAdd(&deg[d], 1);
}

__global__ __launch_bounds__(256) void scanA_kernel(const int* __restrict__ deg,
                                                    int* __restrict__ part, int N) {
    int t = threadIdx.x, lane = t & 63, wid = t >> 6;
    int i = blockIdx.x * 256 + t;
    int v = (i < N) ? deg[i] : 0;
#pragma unroll
    for (int off = 32; off > 0; off >>= 1) v += __shfl_xor(v, off);
    __shared__ int ws4[4];
    if (lane == 0) ws4[wid] = v;
    __syncthreads();
    if (t == 0) part[blockIdx.x] = ws4[0] + ws4[1] + ws4[2] + ws4[3];
}

__global__ __launch_bounds__(1024) void scanB_kernel(int* __restrict__ part,
                                                     int* __restrict__ rowptr,
                                                     int nb, int N) {
    int t = threadIdx.x, lane = t & 63, wid = t >> 6;
    int v = (t < nb) ? part[t] : 0;
    int x = v;
#pragma unroll
    for (int off = 1; off < 64; off <<= 1) {
        int u = __shfl_up(x, off);
        if (lane >= off) x += u;
    }
    __shared__ int wsum[16];
    if (lane == 63) wsum[wid] = x;
    __syncthreads();
    if (wid == 0 && lane < 16) {
        int y = wsum[lane];
#pragma unroll
        for (int off = 1; off < 16; off <<= 1) {
            int u = __shfl_up(y, off);
            if (lane >= off) y += u;
        }
        wsum[lane] = y;
    }
    __syncthreads();
    int base = (wid > 0) ? wsum[wid - 1] : 0;
    int incl = base + x;
    if (t < nb) part[t] = incl - v;  // exclusive block base
    if (t == nb - 1) rowptr[N] = incl;
}

__global__ __launch_bounds__(256) void scanC_kernel(const int* __restrict__ deg,
                                                    const int* __restrict__ part,
                                                    int* __restrict__ rowptr,
                                                    int* __restrict__ cursor, int N) {
    int t = threadIdx.x, lane = t & 63, wid = t >> 6;
    int i = blockIdx.x * 256 + t;
    int v = (i < N) ? deg[i] : 0;
    int x = v;
#pragma unroll
    for (int off = 1; off < 64; off <<= 1) {
        int u = __shfl_up(x, off);
        if (lane >= off) x += u;
    }
    __shared__ int wsum[4];
    if (lane == 63) wsum[wid] = x;
    __syncthreads();
    int base = part[blockIdx.x];
    for (int w = 0; w < wid; ++w) base += wsum[w];
    int excl = base + x - v;
    if (i < N) { rowptr[i] = excl; cursor[i] = excl; }
}

__global__ __launch_bounds__(256) void scatter_kernel(const int* __restrict__ ei,
                                                      int* __restrict__ cursor,
                                                      int* __restrict__ srcs,
                                                      const int* __restrict__ flags,
                                                      int E, int ET, int N) {
    int e = blockIdx.x * 256 + threadIdx.x;
    if (e >= ET) return;
    int s, d;
    if (e < E) {
        if (flags[1]) { s = ei[2 * (size_t)e]; d = ei[2 * (size_t)E + 2 * (size_t)e]; }
        else          { s = ei[e];             d = ei[(size_t)E + e]; }
    } else { s = e - E; d = s; }
    if ((unsigned)s >= (unsigned)N) s = 0;
    if ((unsigned)d >= (unsigned)N) d = 0;
    int pos = atomicAdd(&cursor[d], 1);
    srcs[pos] = s;
}

// ---- K5: fused per-node GATv2 + residual + LayerNorm. One wave per node.
__global__ __launch_bounds__(256) void agg_kernel(
    const bf16* __restrict__ xl, bf16* __restrict__ xr,
    const void* __restrict__ xv, const int* __restrict__ rowptr,
    const int* __restrict__ srcs, const float* __restrict__ smalls,
    int N, const int* __restrict__ flags) {
    int n = blockIdx.x * 4 + (threadIdx.x >> 6);
    if (n >= N) return;
    int lane = threadIdx.x & 63;
    int h = lane >> 4, cg = lane & 15;
    const float* att = smalls + 1024;
    const float* gat_bias = smalls + 1536;
    const float* ln_g = smalls + 1664;
    const float* ln_b = smalls + 1792;

    float att_f[8];
    {
        const float4* ap = (const float4*)(att + (size_t)h * 128 + cg * 8);
        float4 a0 = ap[0], a1 = ap[1];
        att_f[0] = a0.x; att_f[1] = a0.y; att_f[2] = a0.z; att_f[3] = a0.w;
        att_f[4] = a1.x; att_f[5] = a1.y; att_f[6] = a1.z; att_f[7] = a1.w;
    }
    float xr_f[8];
    uint4 xw = ((const uint4*)(xr + (size_t)n * 512))[lane];
    unpack8(xw, xr_f);

    float o[8];
#pragma unroll
    for (int j = 0; j < 8; ++j) o[j] = 0.f;
    float lsum = 0.f;

    int beg = rowptr[n], end = rowptr[n + 1];
    const uint4* xlu = (const uint4*)xl;
    int sA = srcs[beg];                                // deg >= 1 (self-loop)
    int sB = (beg + 1 < end) ? srcs[beg + 1] : sA;
    uint4 lw = xlu[(size_t)sA * 64 + lane];
    for (int i = beg; i < end; ++i) {
        uint4 cur = lw;
        int snext = sB;
        if (i + 2 < end) sB = srcs[i + 2];
        if (i + 1 < end) lw = xlu[(size_t)snext * 64 + lane];
        float v[8];
        unpack8(cur, v);
        float p = 0.f;
#pragma unroll
        for (int j = 0; j < 8; ++j) {
            float t = lrelu(v[j] + xr_f[j]);
            p = fmaf(t, att_f[j], p);
        }
        p += __shfl_xor(p, 1); p += __shfl_xor(p, 2);
        p += __shfl_xor(p, 4); p += __shfl_xor(p, 8);
        float w = __expf(fminf(p, 60.f));
        lsum += w;
#pragma unroll
        for (int j = 0; j < 8; ++j) o[j] = fmaf(w, v[j], o[j]);
    }
    float inv = 0.25f / lsum;
#pragma unroll
    for (int j = 0; j < 8; ++j) o[j] *= inv;
#pragma unroll
    for (int j = 0; j < 8; ++j) {
        o[j] += __shfl_xor(o[j], 16);
        o[j] += __shfl_xor(o[j], 32);
    }
    float xf[8];
    if (flags[0]) {
        uint4 u = *((const uint4*)((const unsigned short*)xv + (size_t)n * 128 + cg * 8));
        unpack8(u, xf);
    } else {
        const float4* xp = (const float4*)((const float*)xv + (size_t)n * 128 + cg * 8);
        float4 a0 = xp[0], a1 = xp[1];
        xf[0] = a0.x; xf[1] = a0.y; xf[2] = a0.z; xf[3] = a0.w;
        xf[4] = a1.x; xf[5] = a1.y; xf[6] = a1.z; xf[7] = a1.w;
    }
    float gb[8];
    {
        const float4* gp = (const float4*)(gat_bias + cg * 8);
        float4 a0 = gp[0], a1 = gp[1];
        gb[0] = a0.x; gb[1] = a0.y; gb[2] = a0.z; gb[3] = a0.w;
        gb[4] = a1.x; gb[5] = a1.y; gb[6] = a1.z; gb[7] = a1.w;
    }
    float vl[8];
    float s1 = 0.f;
#pragma unroll
    for (int j = 0; j < 8; ++j) { vl[j] = xf[j] + o[j] + gb[j]; s1 += vl[j]; }
    s1 += __shfl_xor(s1, 1); s1 += __shfl_xor(s1, 2);
    s1 += __shfl_xor(s1, 4); s1 += __shfl_xor(s1, 8);
    float mu = s1 * (1.f / 128.f);
    float s2 = 0.f;
#pragma unroll
    for (int j = 0; j < 8; ++j) { float d = vl[j] - mu; s2 += d * d; }
    s2 += __shfl_xor(s2, 1); s2 += __shfl_xor(s2, 2);
    s2 += __shfl_xor(s2, 4); s2 += __shfl_xor(s2, 8);
    float rinv = rsqrtf(s2 * (1.f / 128.f) + LN_EPS);
    if (h == 0) {  // lanes 0..15: hn f32 -> bytes 0..511, hn bf16 -> bytes 512..767
        float g[8], bt[8];
        const float4* gp = (const float4*)(ln_g + cg * 8);
        float4 g0 = gp[0], g1 = gp[1];
        g[0] = g0.x; g[1] = g0.y; g[2] = g0.z; g[3] = g0.w;
        g[4] = g1.x; g[5] = g1.y; g[6] = g1.z; g[7] = g1.w;
        const float4* bp = (const float4*)(ln_b + cg * 8);
        float4 b0 = bp[0], b1v = bp[1];
        bt[0] = b0.x; bt[1] = b0.y; bt[2] = b0.z; bt[3] = b0.w;
        bt[4] = b1v.x; bt[5] = b1v.y; bt[6] = b1v.z; bt[7] = b1v.w;
        float hnv[8];
#pragma unroll
        for (int j = 0; j < 8; ++j) hnv[j] = (vl[j] - mu) * rinv * g[j] + bt[j];
        char* rowp = (char*)xr + (size_t)n * 1024;
        float4* hp = (float4*)rowp;
        hp[cg * 2] = make_float4(hnv[0], hnv[1], hnv[2], hnv[3]);
        hp[cg * 2 + 1] = make_float4(hnv[4], hnv[5], hnv[6], hnv[7]);
        uint4 pk;
        pk.x = (unsigned)f2b_bits(hnv[0]) | ((unsigned)f2b_bits(hnv[1]) << 16);
        pk.y = (unsigned)f2b_bits(hnv[2]) | ((unsigned)f2b_bits(hnv[3]) << 16);
        pk.z = (unsigned)f2b_bits(hnv[4]) | ((unsigned)f2b_bits(hnv[5]) << 16);
        pk.w = (unsigned)f2b_bits(hnv[6]) | ((unsigned)f2b_bits(hnv[7]) << 16);
        *(uint4*)(rowp + 512 + cg * 16) = pk;
    }
}

// ---- K6: mid = bf16(lrelu(hn @ W1 + b1)); cols=256, K=128; 128x128 blocks, grid.y=2
__global__ __launch_bounds__(256) void ffn1_mfma_kernel(
    const char* __restrict__ hnrows, const unsigned short* __restrict__ W1t,
    const float* __restrict__ smalls, unsigned short* __restrict__ mid, int N) {
    const float* b1 = smalls + 1920;
    int wid = threadIdx.x >> 6, lane = threadIdx.x & 63;
    int quad = lane >> 4, l16 = lane & 15;
    int m0 = blockIdx.x * 128 + (wid >> 1) * 64;
    int n0 = blockIdx.y * 128 + (wid & 1) * 64;

    int ra[4];
#pragma unroll
    for (int rf = 0; rf < 4; ++rf) {
        int r = m0 + rf * 16 + l16;
        ra[rf] = (r < N) ? r : N - 1;
    }

    f32x4 acc[4][4];
#pragma unroll
    for (int rf = 0; rf < 4; ++rf)
#pragma unroll
        for (int c = 0; c < 4; ++c) acc[rf][c] = (f32x4){0.f, 0.f, 0.f, 0.f};

#pragma unroll
    for (int kk = 0; kk < 128; kk += 32) {
        short8 a[4], b[4];
#pragma unroll
        for (int rf = 0; rf < 4; ++rf)
            a[rf] = ld8b(hnrows + (size_t)ra[rf] * 1024 + 512 + (kk + quad * 8) * 2);
#pragma unroll
        for (int c = 0; c < 4; ++c)
            b[c] = ld8b((const char*)(W1t + (size_t)(n0 + c * 16 + l16) * 128 + kk + quad * 8));
#pragma unroll
        for (int rf = 0; rf < 4; ++rf)
#pragma unroll
            for (int c = 0; c < 4; ++c)
                acc[rf][c] = __builtin_amdgcn_mfma_f32_16x16x32_bf16(a[rf], b[c], acc[rf][c], 0, 0, 0);
    }
#pragma unroll
    for (int c = 0; c < 4; ++c) {
        int col = n0 + c * 16 + l16;
        float bv = b1[col];
#pragma unroll
        for (int rf = 0; rf < 4; ++rf) {
#pragma unroll
            for (int j = 0; j < 4; ++j) {
                int row = m0 + rf * 16 + quad * 4 + j;
                if (row < N) mid[(size_t)row * 256 + col] = f2b_bits(lrelu(acc[rf][c][j] + bv));
            }
        }
    }
}

// ---- K7: out = hn + mid @ W2 + b2; cols=128, K=256; 128x128 blocks
__global__ __launch_bounds__(256) void ffn2_mfma_kernel(
    const unsigned short* __restrict__ mid, const char* __restrict__ hnrows,
    const unsigned short* __restrict__ W2t, const float* __restrict__ smalls,
    void* __restrict__ outv, int N, const int* __restrict__ flags) {
    const float* b2v = smalls + 2176;
    int wid = threadIdx.x >> 6, lane = threadIdx.x & 63;
    int quad = lane >> 4, l16 = lane & 15;
    int m0 = blockIdx.x * 128 + (wid >> 1) * 64;
    int n0 = (wid & 1) * 64;

    int ra[4];
#pragma unroll
    for (int rf = 0; rf < 4; ++rf) {
        int r = m0 + rf * 16 + l16;
        ra[rf] = (r < N) ? r : N - 1;
    }

    f32x4 acc[4][4];
#pragma unroll
    for (int rf = 0; rf < 4; ++rf)
#pragma unroll
        for (int c = 0; c < 4; ++c) acc[rf][c] = (f32x4){0.f, 0.f, 0.f, 0.f};

#pragma unroll
    for (int kk = 0; kk < 256; kk += 32) {
        short8 a[4], b[4];
#pragma unroll
        for (int rf = 0; rf < 4; ++rf)
            a[rf] = ld8b((const char*)(mid + (size_t)ra[rf] * 256 + kk + quad * 8));
#pragma unroll
        for (int c = 0; c < 4; ++c)
            b[c] = ld8b((const char*)(W2t + (size_t)(n0 + c * 16 + l16) * 256 + kk + quad * 8));
#pragma unroll
        for (int rf = 0; rf < 4; ++rf)
#pragma unroll
            for (int c = 0; c < 4; ++c)
                acc[rf][c] = __builtin_amdgcn_mfma_f32_16x16x32_bf16(a[rf], b[c], acc[rf][c], 0, 0, 0);
    }
    int isb = flags[0];
#pragma unroll
    for (int c = 0; c < 4; ++c) {
        int col = n0 + c * 16 + l16;
        float bv = b2v[col];
#pragma unroll
        for (int rf = 0; rf < 4; ++rf) {
#pragma unroll
            for (int j = 0; j < 4; ++j) {
                int row = m0 + rf * 16 + quad * 4 + j;
                if (row < N) {
                    float hval = *(const float*)(hnrows + (size_t)row * 1024 + (size_t)col * 4);
                    float val = hval + acc[rf][c][j] + bv;
                    if (isb) ((unsigned short*)outv)[(size_t)row * 128 + col] = f2b_bits(val);
                    else     ((float*)outv)[(size_t)row * 128 + col] = val;
                }
            }
        }
    }
}

extern "C" void kernel_launch(void* const* d_in, const int* in_sizes, int n_in,
                              void* d_out, int out_size, void* d_ws, size_t ws_size,
                              hipStream_t stream) {
    const void* x = d_in[0];
    const int* ei = (const int*)d_in[1];

    int N = in_sizes[0] / 128;
    int E = in_sizes[1] / 2;
    int ET = E + N;
    int nb = (N + 255) / 256;

    // ---- workspace layout (~105 MB)
    char* base = (char*)d_ws;
    int* flags = (int*)base;
    size_t off = 256;
    float* smalls = (float*)(base + off);               off += 2304 * 4;
    off = (off + 255) & ~(size_t)255;
    unsigned short* Wlt = (unsigned short*)(base + off); off += 512 * 128 * 2;
    unsigned short* Wrt = (unsigned short*)(base + off); off += 512 * 128 * 2;
    unsigned short* W1t = (unsigned short*)(base + off); off += 256 * 128 * 2;
    unsigned short* W2t = (unsigned short*)(base + off); off += 128 * 256 * 2;
    off = (off + 1023) & ~(size_t)1023;
    bf16* xl = (bf16*)(base + off);   off += (size_t)N * 512 * 2;  // -> mid (bf16) after agg
    bf16* xr = (bf16*)(base + off);   off += (size_t)N * 512 * 2;  // rows: hn f32 + hn bf16
    int* srcs = (int*)(base + off);   off += (size_t)ET * 4;
    int* rowptr = (int*)(base + off); off += (size_t)(N + 1) * 4;
    int* deg = (int*)(base + off);    off += (size_t)N * 4;
    int* cursor = (int*)(base + off); off += (size_t)N * 4;
    int* part = (int*)(base + off);   off += (size_t)nb * 4;
    unsigned short* mid = (unsigned short*)xl;
    const char* hnrows = (const char*)xr;

    detect_kernel<<<1, 64, 0, stream>>>((const unsigned*)x, ei, flags, E);

    PrepArgs pa;
    pa.Wl = d_in[2]; pa.Wr = d_in[4]; pa.W1 = d_in[10]; pa.W2 = d_in[12];
    pa.ssrc[0] = d_in[3];  pa.ssrc[1] = d_in[5];  pa.ssrc[2] = d_in[6];
    pa.ssrc[3] = d_in[7];  pa.ssrc[4] = d_in[8];  pa.ssrc[5] = d_in[9];
    pa.ssrc[6] = d_in[11]; pa.ssrc[7] = d_in[13];
    pa.Wlt = Wlt; pa.Wrt = Wrt; pa.W1t = W1t; pa.W2t = W2t;
    pa.smalls = smalls; pa.deg = deg; pa.N = N;
    int px = (65536 > N ? 65536 : N);
    prep_kernel<<<dim3((px + 255) / 256, 6), 256, 0, stream>>>(pa, flags);

    int gtile = (N + 127) / 128;
    proj_mfma_kernel<<<dim3(gtile, 8), 256, 0, stream>>>(x, Wlt, Wrt, smalls, (unsigned short*)xl,
                                                         (unsigned short*)xr, N, flags);

    hist_kernel<<<(E + 255) / 256, 256, 0, stream>>>(ei, deg, flags, E, N);
    scanA_kernel<<<nb, 256, 0, stream>>>(deg, part, N);
    scanB_kernel<<<1, 1024, 0, stream>>>(part, rowptr, nb, N);
    scanC_kernel<<<nb, 256, 0, stream>>>(deg, part, rowptr, cursor, N);
    scatter_kernel<<<(ET + 255) / 256, 256, 0, stream>>>(ei, cursor, srcs, flags, E, ET, N);

    agg_kernel<<<(N + 3) / 4, 256, 0, stream>>>(xl, xr, x, rowptr, srcs, smalls, N, flags);

    ffn1_mfma_kernel<<<dim3(gtile, 2), 256, 0, stream>>>(hnrows, W1t, smalls, mid, N);
    ffn2_mfma_kernel<<<gtile, 256, 0, stream>>>(mid, hnrows, W2t, smalls, d_out, N, flags);
}

// Round 8
// 354.167 us; speedup vs baseline: 1.1460x; 1.1460x over previous
//
#include <hip/hip_runtime.h>
#include <hip/hip_bf16.h>
#include <stdint.h>

typedef __hip_bfloat16 bf16;
typedef __attribute__((ext_vector_type(8))) short short8;
typedef __attribute__((ext_vector_type(4))) float f32x4;

#define NEG 0.2f
#define LN_EPS 1e-5f

// Channel permutation (per 64-block): slot = 64a + 4*l + c  <->  std = 64a + 16c + l
// std(q) for q in a 128/256/512-channel space (64-blocks preserved):
__device__ __host__ __forceinline__ int stdch(int q) {
    return (q & ~63) | (16 * (q & 3)) | ((q & 63) >> 2);
}

__device__ __forceinline__ float bits2f(unsigned b) {  // low 16 bits = bf16
    return __uint_as_float(b << 16);
}
__device__ __forceinline__ float hi2f(unsigned b) {    // high 16 bits = bf16
    return __uint_as_float(b & 0xffff0000u);
}
__device__ __forceinline__ unsigned short f2b_bits(float f) {  // RNE f32->bf16 bits
    unsigned u = __float_as_uint(f);
    unsigned r = u + 0x7fffu + ((u >> 16) & 1u);
    return (unsigned short)(r >> 16);
}
__device__ __forceinline__ float lrelu(float v) {
    return fmaxf(v, 0.f) + NEG * fminf(v, 0.f);
}
__device__ __forceinline__ void unpack8(uint4 u, float* v) {
    v[0] = bits2f(u.x); v[1] = hi2f(u.x);
    v[2] = bits2f(u.y); v[3] = hi2f(u.y);
    v[4] = bits2f(u.z); v[5] = hi2f(u.z);
    v[6] = bits2f(u.w); v[7] = hi2f(u.w);
}

union S8 { uint4 u; short8 s; unsigned short us[8]; };
__device__ __forceinline__ short8 ld8b(const char* p) {
    S8 c; c.u = *(const uint4*)p; return c.s;
}
__device__ __forceinline__ short8 ld8f(const float* p) {
    float4 a = ((const float4*)p)[0], b = ((const float4*)p)[1];
    S8 c;
    c.us[0] = f2b_bits(a.x); c.us[1] = f2b_bits(a.y);
    c.us[2] = f2b_bits(a.z); c.us[3] = f2b_bits(a.w);
    c.us[4] = f2b_bits(b.x); c.us[5] = f2b_bits(b.y);
    c.us[6] = f2b_bits(b.z); c.us[7] = f2b_bits(b.w);
    return c.s;
}

// ---- K0: detect float dtype (flags[0]=1 -> bf16) and index width (flags[1]=1 -> int64)
__global__ void detect_kernel(const unsigned* __restrict__ xw, const int* __restrict__ ei,
                              int* __restrict__ flags, int E) {
    int lane = threadIdx.x;  // 64 threads
    int sane = 0;
    for (int k = 0; k < 4; ++k) {
        unsigned short lo = (unsigned short)(xw[k * 64 + lane] & 0xFFFFu);
        int ex = (lo >> 7) & 0xFF;
        if (lo == 0 || (ex > 100 && ex < 155)) sane++;
    }
#pragma unroll
    for (int off = 32; off > 0; off >>= 1) sane += __shfl_xor(sane, off);
    int nchk = E < 64 ? E : 64;
    int bad = (lane < nchk) ? (ei[2 * lane + 1] != 0) : 0;
    unsigned long long bb = __ballot(bad);
    if (lane == 0) {
        flags[0] = (sane > 200) ? 1 : 0;
        flags[1] = (bb == 0ULL) ? 1 : 0;
    }
}

// ---- K1: prep: W^T transposes (K-permuted for W1/W2), small cvt (att/gb/lng/lnb permuted)
struct PrepArgs {
    const void* Wl; const void* Wr; const void* W1; const void* W2;
    const void* ssrc[8];   // b_l, b_r, att, gat_bias, ln_g, ln_b, b1, b2
    unsigned short* Wlt; unsigned short* Wrt; unsigned short* W1t; unsigned short* W2t;
    float* smalls;         // 2304 floats
    int* deg;
    int N;
};
__device__ __forceinline__ float cvt_one(const void* p, int idx, int isb) {
    return isb ? bits2f(((const unsigned short*)p)[idx]) : ((const float*)p)[idx];
}
__global__ __launch_bounds__(256) void prep_kernel(PrepArgs a, const int* __restrict__ flags) {
    int isb = flags[0];
    int i = blockIdx.x * 256 + threadIdx.x;
    int seg = blockIdx.y;
    if (seg == 0) {         // Wlt[c*128+k] <- W_l[k*512+c]  (std k, std c)
        if (i < 512 * 128) {
            int c = i >> 7, k = i & 127;
            a.Wlt[i] = isb ? ((const unsigned short*)a.Wl)[k * 512 + c]
                           : f2b_bits(((const float*)a.Wl)[k * 512 + c]);
        }
    } else if (seg == 1) {  // Wrt
        if (i < 512 * 128) {
            int c = i >> 7, k = i & 127;
            a.Wrt[i] = isb ? ((const unsigned short*)a.Wr)[k * 512 + c]
                           : f2b_bits(((const float*)a.Wr)[k * 512 + c]);
        }
    } else if (seg == 2) {  // W1t[c*128+q] <- W1[std(q)*256 + c]  (K permuted to hn slot order)
        if (i < 256 * 128) {
            int c = i >> 7, q = i & 127;
            int k = stdch(q);
            a.W1t[i] = isb ? ((const unsigned short*)a.W1)[k * 256 + c]
                           : f2b_bits(((const float*)a.W1)[k * 256 + c]);
        }
    } else if (seg == 3) {  // W2t[c*256+p] <- W2[std(p)*128 + c]  (K permuted to mid slot order)
        if (i < 128 * 256) {
            int c = i >> 8, p = i & 255;
            int k = stdch(p);
            a.W2t[i] = isb ? ((const unsigned short*)a.W2)[k * 128 + c]
                           : f2b_bits(((const float*)a.W2)[k * 128 + c]);
        }
    } else if (seg == 4) {  // deg init (self-loop)
        if (i < a.N) a.deg[i] = 1;
    } else {                // smalls: b_l[0,512) b_r[512,1024) att_p[1024,1536)
                            //         gb_p[1536,1664) lng_p[1664,1792) lnb_p[1792,1920)
                            //         b1[1920,2176) b2[2176,2304)
        if (i < 512) a.smalls[i] = cvt_one(a.ssrc[0], i, isb);
        else if (i < 1024) a.smalls[i] = cvt_one(a.ssrc[1], i - 512, isb);
        else if (i < 1536) {
            int j = i - 1024, h = j >> 7, q = j & 127;
            a.smalls[i] = cvt_one(a.ssrc[2], h * 128 + stdch(q), isb);
        } else if (i < 1664) a.smalls[i] = cvt_one(a.ssrc[3], stdch(i - 1536), isb);
        else if (i < 1792)   a.smalls[i] = cvt_one(a.ssrc[4], stdch(i - 1664), isb);
        else if (i < 1920)   a.smalls[i] = cvt_one(a.ssrc[5], stdch(i - 1792), isb);
        else if (i < 2176)   a.smalls[i] = cvt_one(a.ssrc[6], i - 1920, isb);
        else if (i < 2304)   a.smalls[i] = cvt_one(a.ssrc[7], i - 2176, isb);
    }
}

// ================= MFMA GEMM =================
// A (16x32): lane holds A[m=lane&15][k=quad*8+j]; B (32x16): B[k=quad*8+j][n=lane&15]
// C/D: reg j -> row=quad*4+j, col=lane&15.  (m89/m91-verified)
// Epilogue: lane packs its 4 col-frag values (std cols n0+16c+l16) into one 8B store
// at permuted slot n0+4*l16 -> 16 lanes/quad = 128B fully-written lines (no RMW).

// ---- K2: proj, A-resident: block = 64 rows, 4 waves; iter 0,1 -> xl cols, 2,3 -> xr cols
__global__ __launch_bounds__(256) void proj_mfma_kernel(
    const void* __restrict__ xv, const unsigned short* __restrict__ Wlt,
    const unsigned short* __restrict__ Wrt, const float* __restrict__ smalls,
    unsigned short* __restrict__ xl, unsigned short* __restrict__ xr,
    int N, const int* __restrict__ flags) {
    int isb = flags[0];
    int wid = threadIdx.x >> 6, lane = threadIdx.x & 63;
    int quad = lane >> 4, l16 = lane & 15;
    int m0 = blockIdx.x * 64;

    int ra[4];
#pragma unroll
    for (int rf = 0; rf < 4; ++rf) {
        int r = m0 + rf * 16 + l16;
        ra[rf] = (r < N) ? r : N - 1;
    }
    // A resident: 64 rows x K=128 per wave -> 16 short8 (64 VGPRs)
    short8 A[4][4];
#pragma unroll
    for (int rf = 0; rf < 4; ++rf)
#pragma unroll
        for (int k4 = 0; k4 < 4; ++k4) {
            int ko = k4 * 32 + quad * 8;
            if (isb) A[rf][k4] = ld8b((const char*)xv + ((size_t)ra[rf] * 128 + ko) * 2);
            else     A[rf][k4] = ld8f((const float*)xv + (size_t)ra[rf] * 128 + ko);
        }

    for (int iter = 0; iter < 4; ++iter) {
        const unsigned short* Wt = (iter < 2) ? Wlt : Wrt;
        const float* bias = smalls + ((iter < 2) ? 0 : 512);
        unsigned short* out = (iter < 2) ? xl : xr;
        int n0 = (iter & 1) * 256 + wid * 64;

        f32x4 acc[4][4];
#pragma unroll
        for (int rf = 0; rf < 4; ++rf)
#pragma unroll
            for (int c = 0; c < 4; ++c) acc[rf][c] = (f32x4){0.f, 0.f, 0.f, 0.f};

#pragma unroll
        for (int k4 = 0; k4 < 4; ++k4) {
            short8 b[4];
#pragma unroll
            for (int c = 0; c < 4; ++c)
                b[c] = ld8b((const char*)(Wt + (size_t)(n0 + c * 16 + l16) * 128 + k4 * 32 + quad * 8));
#pragma unroll
            for (int rf = 0; rf < 4; ++rf)
#pragma unroll
                for (int c = 0; c < 4; ++c)
                    acc[rf][c] = __builtin_amdgcn_mfma_f32_16x16x32_bf16(A[rf][k4], b[c], acc[rf][c], 0, 0, 0);
        }
        float bv[4];
#pragma unroll
        for (int c = 0; c < 4; ++c) bv[c] = bias[n0 + c * 16 + l16];
#pragma unroll
        for (int rf = 0; rf < 4; ++rf) {
#pragma unroll
            for (int j = 0; j < 4; ++j) {
                int row = m0 + rf * 16 + quad * 4 + j;
                if (row < N) {
                    uint2 pk;
                    pk.x = (unsigned)f2b_bits(acc[rf][0][j] + bv[0]) |
                           ((unsigned)f2b_bits(acc[rf][1][j] + bv[1]) << 16);
                    pk.y = (unsigned)f2b_bits(acc[rf][2][j] + bv[2]) |
                           ((unsigned)f2b_bits(acc[rf][3][j] + bv[3]) << 16);
                    *(uint2*)(out + (size_t)row * 512 + n0 + 4 * l16) = pk;
                }
            }
        }
    }
}

// ---- CSR build ----
__global__ __launch_bounds__(256) void hist_kernel(const int* __restrict__ ei,
                                                   int* __restrict__ deg,
                                                   const int* __restrict__ flags,
                                                   int E, int N) {
    int e = blockIdx.x * 256 + threadIdx.x;
    if (e >= E) return;
    int d = flags[1] ? ei[2 * (size_t)E + 2 * (size_t)e] : ei[(size_t)E + e];
    if ((unsigned)d >= (unsigned)N) d = 0;
    atomicAdd(&deg[d], 1);
}

__global__ __launch_bounds__(256) void scanA_kernel(const int* __restrict__ deg,
                                                    int* __restrict__ part, int N) {
    int t = threadIdx.x, lane = t & 63, wid = t >> 6;
    int i = blockIdx.x * 256 + t;
    int v = (i < N) ? deg[i] : 0;
#pragma unroll
    for (int off = 32; off > 0; off >>= 1) v += __shfl_xor(v, off);
    __shared__ int ws4[4];
    if (lane == 0) ws4[wid] = v;
    __syncthreads();
    if (t == 0) part[blockIdx.x] = ws4[0] + ws4[1] + ws4[2] + ws4[3];
}

__global__ __launch_bounds__(1024) void scanB_kernel(int* __restrict__ part,
                                                     int* __restrict__ rowptr,
                                                     int nb, int N) {
    int t = threadIdx.x, lane = t & 63, wid = t >> 6;
    int v = (t < nb) ? part[t] : 0;
    int x = v;
#pragma unroll
    for (int off = 1; off < 64; off <<= 1) {
        int u = __shfl_up(x, off);
        if (lane >= off) x += u;
    }
    __shared__ int wsum[16];
    if (lane == 63) wsum[wid] = x;
    __syncthreads();
    if (wid == 0 && lane < 16) {
        int y = wsum[lane];
#pragma unroll
        for (int off = 1; off < 16; off <<= 1) {
            int u = __shfl_up(y, off);
            if (lane >= off) y += u;
        }
        wsum[lane] = y;
    }
    __syncthreads();
    int base = (wid > 0) ? wsum[wid - 1] : 0;
    int incl = base + x;
    if (t < nb) part[t] = incl - v;  // exclusive block base
    if (t == nb - 1) rowptr[N] = incl;
}

__global__ __launch_bounds__(256) void scanC_kernel(const int* __restrict__ deg,
                                                    const int* __restrict__ part,
                                                    int* __restrict__ rowptr,
                                                    int* __restrict__ cursor, int N) {
    int t = threadIdx.x, lane = t & 63, wid = t >> 6;
    int i = blockIdx.x * 256 + t;
    int v = (i < N) ? deg[i] : 0;
    int x = v;
#pragma unroll
    for (int off = 1; off < 64; off <<= 1) {
        int u = __shfl_up(x, off);
        if (lane >= off) x += u;
    }
    __shared__ int wsum[4];
    if (lane == 63) wsum[wid] = x;
    __syncthreads();
    int base = part[blockIdx.x];
    for (int w = 0; w < wid; ++w) base += wsum[w];
    int excl = base + x - v;
    if (i < N) { rowptr[i] = excl; cursor[i] = excl; }
}

__global__ __launch_bounds__(256) void scatter_kernel(const int* __restrict__ ei,
                                                      int* __restrict__ cursor,
                                                      int* __restrict__ srcs,
                                                      const int* __restrict__ flags,
                                                      int E, int ET, int N) {
    int e = blockIdx.x * 256 + threadIdx.x;
    if (e >= ET) return;
    int s, d;
    if (e < E) {
        if (flags[1]) { s = ei[2 * (size_t)e]; d = ei[2 * (size_t)E + 2 * (size_t)e]; }
        else          { s = ei[e];             d = ei[(size_t)E + e]; }
    } else { s = e - E; d = s; }
    if ((unsigned)s >= (unsigned)N) s = 0;
    if ((unsigned)d >= (unsigned)N) d = 0;
    int pos = atomicAdd(&cursor[d], 1);
    srcs[pos] = s;
}

// ---- K5: fused per-node GATv2 + residual + LayerNorm. One wave per node.
// xl/xr/att/gb/lng/lnb all in slot order (transparent); x residual + hn_f32 in std order.
__global__ __launch_bounds__(256) void agg_kernel(
    const bf16* __restrict__ xl, bf16* __restrict__ xr,
    const void* __restrict__ xv, const int* __restrict__ rowptr,
    const int* __restrict__ srcs, const float* __restrict__ smalls,
    int N, const int* __restrict__ flags) {
    int n = blockIdx.x * 4 + (threadIdx.x >> 6);
    if (n >= N) return;
    int lane = threadIdx.x & 63;
    int h = lane >> 4, cg = lane & 15;
    const float* att = smalls + 1024;
    const float* gat_bias = smalls + 1536;
    const float* ln_g = smalls + 1664;
    const float* ln_b = smalls + 1792;

    float att_f[8];
    {
        const float4* ap = (const float4*)(att + (size_t)h * 128 + cg * 8);
        float4 a0 = ap[0], a1 = ap[1];
        att_f[0] = a0.x; att_f[1] = a0.y; att_f[2] = a0.z; att_f[3] = a0.w;
        att_f[4] = a1.x; att_f[5] = a1.y; att_f[6] = a1.z; att_f[7] = a1.w;
    }
    float xr_f[8];
    uint4 xw = ((const uint4*)(xr + (size_t)n * 512))[lane];
    unpack8(xw, xr_f);

    float o[8];
#pragma unroll
    for (int j = 0; j < 8; ++j) o[j] = 0.f;
    float lsum = 0.f;

    int beg = rowptr[n], end = rowptr[n + 1];
    const uint4* xlu = (const uint4*)xl;
    int sA = srcs[beg];                                // deg >= 1 (self-loop)
    int sB = (beg + 1 < end) ? srcs[beg + 1] : sA;
    uint4 lw = xlu[(size_t)sA * 64 + lane];
    for (int i = beg; i < end; ++i) {
        uint4 cur = lw;
        int snext = sB;
        if (i + 2 < end) sB = srcs[i + 2];
        if (i + 1 < end) lw = xlu[(size_t)snext * 64 + lane];
        float v[8];
        unpack8(cur, v);
        float p = 0.f;
#pragma unroll
        for (int j = 0; j < 8; ++j) {
            float t = lrelu(v[j] + xr_f[j]);
            p = fmaf(t, att_f[j], p);
        }
        p += __shfl_xor(p, 1); p += __shfl_xor(p, 2);
        p += __shfl_xor(p, 4); p += __shfl_xor(p, 8);
        float w = __expf(fminf(p, 60.f));
        lsum += w;
#pragma unroll
        for (int j = 0; j < 8; ++j) o[j] = fmaf(w, v[j], o[j]);
    }
    float inv = 0.25f / lsum;
#pragma unroll
    for (int j = 0; j < 8; ++j) o[j] *= inv;
#pragma unroll
    for (int j = 0; j < 8; ++j) {
        o[j] += __shfl_xor(o[j], 16);
        o[j] += __shfl_xor(o[j], 32);
    }
    // residual x (std order): lane's slots t map to std channels bc+16c (+1 for t>=4)
    int bc = 64 * (cg >> 3) + 2 * (cg & 7);
    float xf[8];
    if (flags[0]) {
#pragma unroll
        for (int c = 0; c < 4; ++c) {
            unsigned d = *(const unsigned*)((const unsigned short*)xv + (size_t)n * 128 + bc + 16 * c);
            xf[c] = bits2f(d); xf[c + 4] = hi2f(d);
        }
    } else {
#pragma unroll
        for (int c = 0; c < 4; ++c) {
            float2 f = *(const float2*)((const float*)xv + (size_t)n * 128 + bc + 16 * c);
            xf[c] = f.x; xf[c + 4] = f.y;
        }
    }
    float gb[8];
    {
        const float4* gp = (const float4*)(gat_bias + cg * 8);
        float4 a0 = gp[0], a1 = gp[1];
        gb[0] = a0.x; gb[1] = a0.y; gb[2] = a0.z; gb[3] = a0.w;
        gb[4] = a1.x; gb[5] = a1.y; gb[6] = a1.z; gb[7] = a1.w;
    }
    float vl[8];
    float s1 = 0.f;
#pragma unroll
    for (int j = 0; j < 8; ++j) { vl[j] = xf[j] + o[j] + gb[j]; s1 += vl[j]; }
    s1 += __shfl_xor(s1, 1); s1 += __shfl_xor(s1, 2);
    s1 += __shfl_xor(s1, 4); s1 += __shfl_xor(s1, 8);
    float mu = s1 * (1.f / 128.f);
    float s2 = 0.f;
#pragma unroll
    for (int j = 0; j < 8; ++j) { float d = vl[j] - mu; s2 += d * d; }
    s2 += __shfl_xor(s2, 1); s2 += __shfl_xor(s2, 2);
    s2 += __shfl_xor(s2, 4); s2 += __shfl_xor(s2, 8);
    float rinv = rsqrtf(s2 * (1.f / 128.f) + LN_EPS);
    if (h == 0) {  // lanes 0..15: hn f32 std -> bytes 0..511; hn bf16 slot -> bytes 512..767
        float g[8], bt[8];
        const float4* gp = (const float4*)(ln_g + cg * 8);
        float4 g0 = gp[0], g1 = gp[1];
        g[0] = g0.x; g[1] = g0.y; g[2] = g0.z; g[3] = g0.w;
        g[4] = g1.x; g[5] = g1.y; g[6] = g1.z; g[7] = g1.w;
        const float4* bp = (const float4*)(ln_b + cg * 8);
        float4 b0 = bp[0], b1v = bp[1];
        bt[0] = b0.x; bt[1] = b0.y; bt[2] = b0.z; bt[3] = b0.w;
        bt[4] = b1v.x; bt[5] = b1v.y; bt[6] = b1v.z; bt[7] = b1v.w;
        float hnv[8];
#pragma unroll
        for (int j = 0; j < 8; ++j) hnv[j] = (vl[j] - mu) * rinv * g[j] + bt[j];
        char* rowp = (char*)xr + (size_t)n * 1024;
        float* hp = (float*)rowp;
#pragma unroll
        for (int c = 0; c < 4; ++c) {
            float2 f; f.x = hnv[c]; f.y = hnv[c + 4];
            *(float2*)(hp + bc + 16 * c) = f;   // std channels bc+16c, bc+16c+1
        }
        uint4 pk;  // slot order
        pk.x = (unsigned)f2b_bits(hnv[0]) | ((unsigned)f2b_bits(hnv[1]) << 16);
        pk.y = (unsigned)f2b_bits(hnv[2]) | ((unsigned)f2b_bits(hnv[3]) << 16);
        pk.z = (unsigned)f2b_bits(hnv[4]) | ((unsigned)f2b_bits(hnv[5]) << 16);
        pk.w = (unsigned)f2b_bits(hnv[6]) | ((unsigned)f2b_bits(hnv[7]) << 16);
        *(uint4*)(rowp + 512 + cg * 16) = pk;
    }
}

// ---- K6: mid = lrelu(hn @ W1 + b1), stored in slot order; A-resident, block 64 rows
__global__ __launch_bounds__(256) void ffn1_mfma_kernel(
    const char* __restrict__ hnrows, const unsigned short* __restrict__ W1t,
    const float* __restrict__ smalls, unsigned short* __restrict__ mid, int N) {
    const float* b1 = smalls + 1920;
    int wid = threadIdx.x >> 6, lane = threadIdx.x & 63;
    int quad = lane >> 4, l16 = lane & 15;
    int m0 = blockIdx.x * 64;
    int n0 = wid * 64;

    int ra[4];
#pragma unroll
    for (int rf = 0; rf < 4; ++rf) {
        int r = m0 + rf * 16 + l16;
        ra[rf] = (r < N) ? r : N - 1;
    }
    short8 A[4][4];
#pragma unroll
    for (int rf = 0; rf < 4; ++rf)
#pragma unroll
        for (int k4 = 0; k4 < 4; ++k4)
            A[rf][k4] = ld8b(hnrows + (size_t)ra[rf] * 1024 + 512 + (k4 * 32 + quad * 8) * 2);

    f32x4 acc[4][4];
#pragma unroll
    for (int rf = 0; rf < 4; ++rf)
#pragma unroll
        for (int c = 0; c < 4; ++c) acc[rf][c] = (f32x4){0.f, 0.f, 0.f, 0.f};

#pragma unroll
    for (int k4 = 0; k4 < 4; ++k4) {
        short8 b[4];
#pragma unroll
        for (int c = 0; c < 4; ++c)
            b[c] = ld8b((const char*)(W1t + (size_t)(n0 + c * 16 + l16) * 128 + k4 * 32 + quad * 8));
#pragma unroll
        for (int rf = 0; rf < 4; ++rf)
#pragma unroll
            for (int c = 0; c < 4; ++c)
                acc[rf][c] = __builtin_amdgcn_mfma_f32_16x16x32_bf16(A[rf][k4], b[c], acc[rf][c], 0, 0, 0);
    }
    float bv[4];
#pragma unroll
    for (int c = 0; c < 4; ++c) bv[c] = b1[n0 + c * 16 + l16];
#pragma unroll
    for (int rf = 0; rf < 4; ++rf) {
#pragma unroll
        for (int j = 0; j < 4; ++j) {
            int row = m0 + rf * 16 + quad * 4 + j;
            if (row < N) {
                uint2 pk;
                pk.x = (unsigned)f2b_bits(lrelu(acc[rf][0][j] + bv[0])) |
                       ((unsigned)f2b_bits(lrelu(acc[rf][1][j] + bv[1])) << 16);
                pk.y = (unsigned)f2b_bits(lrelu(acc[rf][2][j] + bv[2])) |
                       ((unsigned)f2b_bits(lrelu(acc[rf][3][j] + bv[3])) << 16);
                *(uint2*)(mid + (size_t)row * 256 + n0 + 4 * l16) = pk;
            }
        }
    }
}

// ---- K7: out = hn + mid @ W2 + b2 (std layout); K=256 over mid slots; 128x128 blocks
__global__ __launch_bounds__(256) void ffn2_mfma_kernel(
    const unsigned short* __restrict__ mid, const char* __restrict__ hnrows,
    const unsigned short* __restrict__ W2t, const float* __restrict__ smalls,
    void* __restrict__ outv, int N, const int* __restrict__ flags) {
    const float* b2v = smalls + 2176;
    int wid = threadIdx.x >> 6, lane = threadIdx.x & 63;
    int quad = lane >> 4, l16 = lane & 15;
    int m0 = blockIdx.x * 128 + (wid >> 1) * 64;
    int n0 = (wid & 1) * 64;

    int ra[4];
#pragma unroll
    for (int rf = 0; rf < 4; ++rf) {
        int r = m0 + rf * 16 + l16;
        ra[rf] = (r < N) ? r : N - 1;
    }

    f32x4 acc[4][4];
#pragma unroll
    for (int rf = 0; rf < 4; ++rf)
#pragma unroll
        for (int c = 0; c < 4; ++c) acc[rf][c] = (f32x4){0.f, 0.f, 0.f, 0.f};

#pragma unroll
    for (int kk = 0; kk < 256; kk += 32) {
        short8 a[4], b[4];
#pragma unroll
        for (int rf = 0; rf < 4; ++rf)
            a[rf] = ld8b((const char*)(mid + (size_t)ra[rf] * 256 + kk + quad * 8));
#pragma unroll
        for (int c = 0; c < 4; ++c)
            b[c] = ld8b((const char*)(W2t + (size_t)(n0 + c * 16 + l16) * 256 + kk + quad * 8));
#pragma unroll
        for (int rf = 0; rf < 4; ++rf)
#pragma unroll
            for (int c = 0; c < 4; ++c)
                acc[rf][c] = __builtin_amdgcn_mfma_f32_16x16x32_bf16(a[rf], b[c], acc[rf][c], 0, 0, 0);
    }
    int isb = flags[0];
#pragma unroll
    for (int c = 0; c < 4; ++c) {
        int col = n0 + c * 16 + l16;
        float bv = b2v[col];
#pragma unroll
        for (int rf = 0; rf < 4; ++rf) {
#pragma unroll
            for (int j = 0; j < 4; ++j) {
                int row = m0 + rf * 16 + quad * 4 + j;
                if (row < N) {
                    float hval = *(const float*)(hnrows + (size_t)row * 1024 + (size_t)col * 4);
                    float val = hval + acc[rf][c][j] + bv;
                    if (isb) ((unsigned short*)outv)[(size_t)row * 128 + col] = f2b_bits(val);
                    else     ((float*)outv)[(size_t)row * 128 + col] = val;
                }
            }
        }
    }
}

extern "C" void kernel_launch(void* const* d_in, const int* in_sizes, int n_in,
                              void* d_out, int out_size, void* d_ws, size_t ws_size,
                              hipStream_t stream) {
    const void* x = d_in[0];
    const int* ei = (const int*)d_in[1];

    int N = in_sizes[0] / 128;
    int E = in_sizes[1] / 2;
    int ET = E + N;
    int nb = (N + 255) / 256;

    // ---- workspace layout (~105 MB)
    char* base = (char*)d_ws;
    int* flags = (int*)base;
    size_t off = 256;
    float* smalls = (float*)(base + off);               off += 2304 * 4;
    off = (off + 255) & ~(size_t)255;
    unsigned short* Wlt = (unsigned short*)(base + off); off += 512 * 128 * 2;
    unsigned short* Wrt = (unsigned short*)(base + off); off += 512 * 128 * 2;
    unsigned short* W1t = (unsigned short*)(base + off); off += 256 * 128 * 2;
    unsigned short* W2t = (unsigned short*)(base + off); off += 128 * 256 * 2;
    off = (off + 1023) & ~(size_t)1023;
    bf16* xl = (bf16*)(base + off);   off += (size_t)N * 512 * 2;  // -> mid (bf16) after agg
    bf16* xr = (bf16*)(base + off);   off += (size_t)N * 512 * 2;  // rows: hn f32 (std) + hn bf16 (slot)
    int* srcs = (int*)(base + off);   off += (size_t)ET * 4;
    int* rowptr = (int*)(base + off); off += (size_t)(N + 1) * 4;
    int* deg = (int*)(base + off);    off += (size_t)N * 4;
    int* cursor = (int*)(base + off); off += (size_t)N * 4;
    int* part = (int*)(base + off);   off += (size_t)nb * 4;
    unsigned short* mid = (unsigned short*)xl;
    const char* hnrows = (const char*)xr;

    detect_kernel<<<1, 64, 0, stream>>>((const unsigned*)x, ei, flags, E);

    PrepArgs pa;
    pa.Wl = d_in[2]; pa.Wr = d_in[4]; pa.W1 = d_in[10]; pa.W2 = d_in[12];
    pa.ssrc[0] = d_in[3];  pa.ssrc[1] = d_in[5];  pa.ssrc[2] = d_in[6];
    pa.ssrc[3] = d_in[7];  pa.ssrc[4] = d_in[8];  pa.ssrc[5] = d_in[9];
    pa.ssrc[6] = d_in[11]; pa.ssrc[7] = d_in[13];
    pa.Wlt = Wlt; pa.Wrt = Wrt; pa.W1t = W1t; pa.W2t = W2t;
    pa.smalls = smalls; pa.deg = deg; pa.N = N;
    int px = (65536 > N ? 65536 : N);
    prep_kernel<<<dim3((px + 255) / 256, 6), 256, 0, stream>>>(pa, flags);

    int g64 = (N + 63) / 64;
    proj_mfma_kernel<<<g64, 256, 0, stream>>>(x, Wlt, Wrt, smalls, (unsigned short*)xl,
                                              (unsigned short*)xr, N, flags);

    hist_kernel<<<(E + 255) / 256, 256, 0, stream>>>(ei, deg, flags, E, N);
    scanA_kernel<<<nb, 256, 0, stream>>>(deg, part, N);
    scanB_kernel<<<1, 1024, 0, stream>>>(part, rowptr, nb, N);
    scanC_kernel<<<nb, 256, 0, stream>>>(deg, part, rowptr, cursor, N);
    scatter_kernel<<<(ET + 255) / 256, 256, 0, stream>>>(ei, cursor, srcs, flags, E, ET, N);

    agg_kernel<<<(N + 3) / 4, 256, 0, stream>>>(xl, xr, x, rowptr, srcs, smalls, N, flags);

    ffn1_mfma_kernel<<<g64, 256, 0, stream>>>(hnrows, W1t, smalls, mid, N);
    ffn2_mfma_kernel<<<(N + 127) / 128, 256, 0, stream>>>(mid, hnrows, W2t, smalls, d_out, N, flags);
}